// Round 11
// baseline (95.081 us; speedup 1.0000x reference)
//
#include <hip/hip_runtime.h>

#define ALPHA 0.25f
#define EPS   1e-8f
// COST_CLASS=2, COST_BBOX=5, COST_GIOU=2

// Problem constants (from setup_inputs): bs=16, Q=900, C=80, g_size=3
constexpr int BS = 16;
constexpr int QN = 900;
constexpr int CN = 80;
constexpr int GS = 3;
constexpr int ROWS = GS;                     // 3 pred rows = 1 query-group per WAVE
constexpr int CC_STRIDE = 4;                 // class-cost row padded to 4 floats (16B)
constexpr int WPB = 5;                       // waves (= query-groups) per block
constexpr int NT_THREADS = WPB * 64;         // 320

// ---------------------------------------------------------------------------
// v8: one query-group per WAVE, zero barriers, 25-iteration steady state.
//  v7 (full unroll) FAILED the post-timing determinism check -> abandoned;
//  back to the rolled depth-1-prefetch body verified in v3/v5/v6.
//  v6 model: ~4us of issue work measured at ~31us -> ~85% idle. Cause: 4800
//  tiny barrier-coupled blocks, 5 iterations each; prologue latency + barrier
//  + block churn dominate. v8 re-shards: each wave owns one query-group and
//  its private 80x4 LDS cc-slice (same-wave ds_write->ds_read ordering via
//  lgkmcnt, NO __syncthreads), then 1600/64 = 25 exact t-iterations.
//  Grid 60x16 = 960 blocks x 5 independent waves: whole grid resident
//  (3.75 blocks/CU), no churn, prologue amortized 25:1 (was 5:1).
//  Per-pair math byte-identical to v5/v6 (scalar xyxy min/max, rcpf divide).
// ---------------------------------------------------------------------------
template<int NITER>   // >0: exact compile-time trip count; 0: generic runtime
__global__ __launch_bounds__(NT_THREADS, 4) void fused_cost_kernel(
    const float* __restrict__ pred_logits,  // [BS*QN, CN]
    const float* __restrict__ pred_boxes,   // [BS*QN, 4] cxcywh
    const int*   __restrict__ tgt_labels,   // [T]
    const float* __restrict__ tgt_boxes,    // [T, 4] cxcywh
    float*       __restrict__ out,          // [BS, QN/GS, T]
    int T)
{
    __shared__ __align__(16) float s_cc[WPB][CN * CC_STRIDE];  // 5 x 1280 B

    const int tid  = threadIdx.x;
    const int w    = tid >> 6;              // wave id 0..4
    const int lane = tid & 63;
    const int qg   = blockIdx.x * WPB + w;  // this wave's query-group
    const int b    = blockIdx.y;
    const int n0   = b * QN + qg * GS;      // first of 3 pred rows

    // ---- per-wave focal class-cost prologue into this wave's LDS slice ----
    // 240 logits over 64 lanes (4 strided steps). Only THIS wave reads the
    // slice, and a wave's own ds_write->ds_read is ordered by lgkmcnt the
    // compiler inserts (may-alias dep on s_cc) -> no __syncthreads anywhere.
    const float* lg0 = pred_logits + (size_t)n0 * CN;
    float* const sc = s_cc[w];
    for (int idx = lane; idx < ROWS * CN; idx += 64) {
        const float x = lg0[idx];
        const int r = idx / CN;
        const int c = idx - r * CN;
        float p = __fdividef(1.0f, 1.0f + __expf(-x));  // sigmoid
        float omp = 1.0f - p;
        float pos = ALPHA * omp * omp * (-__logf(p + EPS));
        float neg = (1.0f - ALPHA) * p * p * (-__logf(omp + EPS));
        sc[c * CC_STRIDE + r] = pos - neg;
    }

    // ---- pred rows -> wave-uniform registers (scalar, xyxy + extras) ----
    float Px0[ROWS], Py0[ROWS], Px1[ROWS], Py1[ROWS];
    float Pcx2[ROWS], Pcy2[ROWS], Pw[ROWS], Ph[ROWS], Pa[ROWS];
    #pragma unroll
    for (int r = 0; r < ROWS; ++r) {
        const float4 pb = ((const float4*)pred_boxes)[n0 + r];
        Pw[r]   = pb.z;               Ph[r]   = pb.w;
        Pa[r]   = pb.z * pb.w;
        Pcx2[r] = pb.x + pb.x;        Pcy2[r] = pb.y + pb.y;
        Px0[r]  = pb.x - 0.5f * pb.z; Py0[r]  = pb.y - 0.5f * pb.w;
        Px1[r]  = pb.x + 0.5f * pb.z; Py1[r]  = pb.y + 0.5f * pb.w;
    }

    float* const o0 = out + (size_t)(b * (QN / GS) + qg) * T;

    const int nIter = (NITER > 0) ? NITER : ((T + 63) / 64);

    int t = lane;
    int tl = (NITER > 0) ? t : ((t < T) ? t : (T - 1));  // clamped load idx
    float4 tr  = ((const float4*)tgt_boxes)[tl];
    int    lab = tgt_labels[tl];

    for (int it = 0; it < nIter; ++it) {
        // ---- depth-1 prefetch of next target (clamped; verified pattern) ----
        const int tn = t + 64;
        const int tc = (tn < T) ? tn : tl;
        const float4 trn  = ((const float4*)tgt_boxes)[tc];
        const int    labn = tgt_labels[tc];

        // ---- gather the 3 class costs for this label: 1x ds_read_b128 ----
        const float4 ccq = *((const float4*)&sc[lab * CC_STRIDE]);
        const float ccv[ROWS] = { ccq.x, ccq.y, ccq.z };

        // per-t scalars
        const float tx0 = tr.x - 0.5f * tr.z, ty0 = tr.y - 0.5f * tr.w;
        const float tx1 = tr.x + 0.5f * tr.z, ty1 = tr.y + 0.5f * tr.w;
        const float ta  = tr.z * tr.w;
        const float tcx2 = tr.x + tr.x, tcy2 = tr.y + tr.y;

        const bool doWrite = (NITER > 0) || (t < T);

        float m = -3.402823466e+38f;
        #pragma unroll
        for (int i = 0; i < ROWS; ++i) {
            // intersection
            const float ix0 = fmaxf(Px0[i], tx0);
            const float iy0 = fmaxf(Py0[i], ty0);
            const float ix1 = fminf(Px1[i], tx1);
            const float iy1 = fminf(Py1[i], ty1);
            const float iw  = fmaxf(ix1 - ix0, 0.0f);
            const float ih  = fmaxf(iy1 - iy0, 0.0f);
            const float inter = iw * ih;

            // enclosing box
            const float ex0 = fminf(Px0[i], tx0);
            const float ey0 = fminf(Py0[i], ty0);
            const float ex1 = fmaxf(Px1[i], tx1);
            const float ey1 = fmaxf(Py1[i], ty1);
            const float earea = (ex1 - ex0) * (ey1 - ey0);

            // union
            const float uni = (Pa[i] + ta) - inter;

            // L1 in cxcywh space
            const float h1 = fabsf(Pcx2[i] - tcx2) + fabsf(Pcy2[i] - tcy2);
            const float h2 = fabsf(Pw[i] - tr.z) + fabsf(Ph[i] - tr.w);
            const float l1 = fmaf(0.5f, h1, h2);

            // giou fraction: q = (inter*earea + uni^2)/(uni*earea)
            const float num = fmaf(inter, earea, uni * uni);
            const float den = uni * earea;
            const float q   = num * __builtin_amdgcn_rcpf(den);

            // cost = 5*l1 + 2*cc + 2 - 2*q
            const float cost = fmaf(5.0f, l1,
                                fmaf(2.0f, ccv[i], fmaf(-2.0f, q, 2.0f)));
            m = fmaxf(m, cost);
        }
        if (doWrite)
            __builtin_nontemporal_store(m, o0 + t);

        t = tn; tl = tc; tr = trn; lab = labn;
    }
}

extern "C" void kernel_launch(void* const* d_in, const int* in_sizes, int n_in,
                              void* d_out, int out_size, void* d_ws, size_t ws_size,
                              hipStream_t stream) {
    const float* pred_logits = (const float*)d_in[0];   // [16,900,80]
    const float* pred_boxes  = (const float*)d_in[1];   // [16,900,4]
    const int*   tgt_labels  = (const int*)d_in[2];     // [T]
    const float* tgt_boxes   = (const float*)d_in[3];   // [T,4]
    // d_in[4] = g_size (=3, hard-coded as GS)

    const int T = in_sizes[2];
    float* out = (float*)d_out;

    dim3 grid((QN / GS) / WPB, BS);                      // 60 x 16 = 960
    if (T == 64 * 25) {
        fused_cost_kernel<25><<<grid, NT_THREADS, 0, stream>>>(
            pred_logits, pred_boxes, tgt_labels, tgt_boxes, out, T);
    } else {
        fused_cost_kernel<0><<<grid, NT_THREADS, 0, stream>>>(
            pred_logits, pred_boxes, tgt_labels, tgt_boxes, out, T);
    }
}

// Round 12
// 91.903 us; speedup vs baseline: 1.0346x; 1.0346x over previous
//
#include <hip/hip_runtime.h>

#define ALPHA 0.25f
#define EPS   1e-8f
// COST_CLASS=2, COST_BBOX=5, COST_GIOU=2

// Problem constants (from setup_inputs): bs=16, Q=900, C=80, g_size=3
constexpr int BS = 16;
constexpr int QN = 900;
constexpr int CN = 80;
constexpr int GS = 3;
constexpr int ROWS = GS;                     // 3 pred rows = 1 query-group per block
constexpr int CC_STRIDE = 4;                 // class-cost row padded to 4 floats (16B)
constexpr int NT_THREADS = 320;              // 5 waves

// ---------------------------------------------------------------------------
// v9: v6 (champion, 90.5us e2e / kernel ~31us) + two independent t-streams
//  per thread.
//  Evidence: v5(1200blk)=39.6 -> v6(4800blk)=31 -> v8(960blk)=35.8 kernel us:
//  resident waves/SIMD controls perf; v6's structure is best. Its residual
//  stall is per-iteration dependency latency (ds_read ~120cy + ~15-deep VALU
//  chain) not covered at ~7.5 waves/SIMD. v7's 5-deep full unroll broke
//  post-timing determinism -> NOT repeated. Instead: 2 rolled streams,
//  A=[0,960) 3 iters + B=[960,1600) 2 iters, schedule (A0B0)(A1B1)(A2) with
//  the v6-verified depth-1 prefetch per stream. 2 independent bodies in
//  flight, all indices compile-time, per-t math byte-identical to v5/v6.
// ---------------------------------------------------------------------------
template<bool FAST>   // FAST: T==1600 specialization
__global__ __launch_bounds__(NT_THREADS, 4) void fused_cost_kernel(
    const float* __restrict__ pred_logits,  // [BS*QN, CN]
    const float* __restrict__ pred_boxes,   // [BS*QN, 4] cxcywh
    const int*   __restrict__ tgt_labels,   // [T]
    const float* __restrict__ tgt_boxes,    // [T, 4] cxcywh
    float*       __restrict__ out,          // [BS, QN/GS, T]
    int T)
{
    __shared__ __align__(16) float s_cc_t[CN * CC_STRIDE];  // [80][4] = 1280 B

    const int tid = threadIdx.x;
    const int qg0 = blockIdx.x;             // one query-group per block
    const int b   = blockIdx.y;
    const int n0  = b * QN + qg0 * GS;      // first of 3 pred rows

    // ---- focal class-cost rows from logits, transposed into LDS (v6 exact) ----
    const float* lg0 = pred_logits + (size_t)n0 * CN;
    if (tid < (ROWS * CN) / 4) {            // 60 float4 loads
        const float4 x4 = ((const float4*)lg0)[tid];
        const int base = tid * 4;
        const int r = base / CN;
        const int c = base - r * CN;        // CN%4==0 -> all 4 share row r
        const float xs[4] = { x4.x, x4.y, x4.z, x4.w };
        #pragma unroll
        for (int i = 0; i < 4; ++i) {
            float p = __fdividef(1.0f, 1.0f + __expf(-xs[i]));  // sigmoid
            float omp = 1.0f - p;
            float pos = ALPHA * omp * omp * (-__logf(p + EPS));
            float neg = (1.0f - ALPHA) * p * p * (-__logf(omp + EPS));
            s_cc_t[(c + i) * CC_STRIDE + r] = pos - neg;
        }
    }

    // ---- pred rows -> wave-uniform registers (v6 exact) ----
    float Px0[ROWS], Py0[ROWS], Px1[ROWS], Py1[ROWS];
    float Pcx2[ROWS], Pcy2[ROWS], Pw[ROWS], Ph[ROWS], Pa[ROWS];
    #pragma unroll
    for (int r = 0; r < ROWS; ++r) {
        const float4 pb = ((const float4*)pred_boxes)[n0 + r];
        Pw[r]   = pb.z;               Ph[r]   = pb.w;
        Pa[r]   = pb.z * pb.w;
        Pcx2[r] = pb.x + pb.x;        Pcy2[r] = pb.y + pb.y;
        Px0[r]  = pb.x - 0.5f * pb.z; Py0[r]  = pb.y - 0.5f * pb.w;
        Px1[r]  = pb.x + 0.5f * pb.z; Py1[r]  = pb.y + 0.5f * pb.w;
    }
    __syncthreads();

    float* const o0 = out + (size_t)(b * (QN / GS) + qg0) * T;

    // body: per-t cost + group-max + store (byte-identical math to v5/v6)
    auto body = [&](int t, const float4 tr, int lab) {
        const float4 ccq = *((const float4*)&s_cc_t[lab * CC_STRIDE]);
        const float ccv[ROWS] = { ccq.x, ccq.y, ccq.z };

        const float tx0 = tr.x - 0.5f * tr.z, ty0 = tr.y - 0.5f * tr.w;
        const float tx1 = tr.x + 0.5f * tr.z, ty1 = tr.y + 0.5f * tr.w;
        const float ta  = tr.z * tr.w;
        const float tcx2 = tr.x + tr.x, tcy2 = tr.y + tr.y;

        float m = -3.402823466e+38f;
        #pragma unroll
        for (int i = 0; i < ROWS; ++i) {
            const float ix0 = fmaxf(Px0[i], tx0);
            const float iy0 = fmaxf(Py0[i], ty0);
            const float ix1 = fminf(Px1[i], tx1);
            const float iy1 = fminf(Py1[i], ty1);
            const float iw  = fmaxf(ix1 - ix0, 0.0f);
            const float ih  = fmaxf(iy1 - iy0, 0.0f);
            const float inter = iw * ih;

            const float ex0 = fminf(Px0[i], tx0);
            const float ey0 = fminf(Py0[i], ty0);
            const float ex1 = fmaxf(Px1[i], tx1);
            const float ey1 = fmaxf(Py1[i], ty1);
            const float earea = (ex1 - ex0) * (ey1 - ey0);

            const float uni = (Pa[i] + ta) - inter;

            const float h1 = fabsf(Pcx2[i] - tcx2) + fabsf(Pcy2[i] - tcy2);
            const float h2 = fabsf(Pw[i] - tr.z) + fabsf(Ph[i] - tr.w);
            const float l1 = fmaf(0.5f, h1, h2);

            const float num = fmaf(inter, earea, uni * uni);
            const float den = uni * earea;
            const float q   = num * __builtin_amdgcn_rcpf(den);

            const float cost = fmaf(5.0f, l1,
                                fmaf(2.0f, ccv[i], fmaf(-2.0f, q, 2.0f)));
            m = fmaxf(m, cost);
        }
        __builtin_nontemporal_store(m, o0 + t);
    };

    if constexpr (FAST) {
        // two streams: A = tid+{0,320,640}, B = tid+{960,1280}
        const int tA = tid, tB = tid + 960;

        float4 trA0 = ((const float4*)tgt_boxes)[tA];
        int    laA0 = tgt_labels[tA];
        float4 trB0 = ((const float4*)tgt_boxes)[tB];
        int    laB0 = tgt_labels[tB];

        // double-iteration 0: prefetch A1,B1; compute A0,B0
        float4 trA1 = ((const float4*)tgt_boxes)[tA + 320];
        int    laA1 = tgt_labels[tA + 320];
        float4 trB1 = ((const float4*)tgt_boxes)[tB + 320];
        int    laB1 = tgt_labels[tB + 320];
        body(tA, trA0, laA0);
        body(tB, trB0, laB0);

        // double-iteration 1: prefetch A2; compute A1,B1
        float4 trA2 = ((const float4*)tgt_boxes)[tA + 640];
        int    laA2 = tgt_labels[tA + 640];
        body(tA + 320, trA1, laA1);
        body(tB + 320, trB1, laB1);

        // tail: compute A2
        body(tA + 640, trA2, laA2);
    } else {
        // generic rolled loop with depth-1 prefetch (v6-verified pattern)
        const int nIter = (T + NT_THREADS - 1) / NT_THREADS;
        int t = tid;
        int tl = (t < T) ? t : (T - 1);
        float4 tr  = ((const float4*)tgt_boxes)[tl];
        int    lab = tgt_labels[tl];
        for (int it = 0; it < nIter; ++it) {
            const int tn = t + NT_THREADS;
            const int tc = (tn < T) ? tn : tl;
            const float4 trn  = ((const float4*)tgt_boxes)[tc];
            const int    labn = tgt_labels[tc];
            if (t < T) body(t, tr, lab);
            t = tn; tl = tc; tr = trn; lab = labn;
        }
    }
}

extern "C" void kernel_launch(void* const* d_in, const int* in_sizes, int n_in,
                              void* d_out, int out_size, void* d_ws, size_t ws_size,
                              hipStream_t stream) {
    const float* pred_logits = (const float*)d_in[0];   // [16,900,80]
    const float* pred_boxes  = (const float*)d_in[1];   // [16,900,4]
    const int*   tgt_labels  = (const int*)d_in[2];     // [T]
    const float* tgt_boxes   = (const float*)d_in[3];   // [T,4]
    // d_in[4] = g_size (=3, hard-coded as GS)

    const int T = in_sizes[2];
    float* out = (float*)d_out;

    dim3 grid(QN / GS, BS);                              // 300 x 16 = 4800
    if (T == 1600) {
        fused_cost_kernel<true><<<grid, NT_THREADS, 0, stream>>>(
            pred_logits, pred_boxes, tgt_labels, tgt_boxes, out, T);
    } else {
        fused_cost_kernel<false><<<grid, NT_THREADS, 0, stream>>>(
            pred_logits, pred_boxes, tgt_labels, tgt_boxes, out, T);
    }
}

// Round 13
// 89.594 us; speedup vs baseline: 1.0612x; 1.0258x over previous
//
#include <hip/hip_runtime.h>

#define ALPHA 0.25f
#define EPS   1e-8f
// COST_CLASS=2, COST_BBOX=5, COST_GIOU=2

// Problem constants (from setup_inputs): bs=16, Q=900, C=80, g_size=3
constexpr int BS = 16;
constexpr int QN = 900;
constexpr int CN = 80;
constexpr int GS = 3;
constexpr int ROWS = GS;                     // 3 pred rows = 1 query-group per block
constexpr int CC_STRIDE = 4;                 // class-cost row padded to 4 floats (16B)
constexpr int NT_THREADS = 320;              // 5 waves; 1600/320 = 5 exact iters

// ---------------------------------------------------------------------------
// v10: v6 (champion, kernel ~31us) + depth-2 target prefetch + wide prologue.
//  Ledger: v5(1200blk)=39.6 / v6(4800blk)=31 / v8(960blk)=35.8 / v9(2-stream
//  ILP)=~30.5 (neutral). TLP is the proven lever; extra BODIES in flight do
//  nothing. Residual theory: iteration-head stall on the target load -- body
//  consumes tr immediately, depth-1 prefetch covers only ~250cy of a 400-600cy
//  effective L2 latency at 30 waves/CU. v10 prefetches DEPTH-2 (t+640 while
//  computing t): ~500cy cover for +6 VGPR, single stream, v6-verified clamp
//  pattern. Prologue: 240 threads x 1 logit (was 60 x 4) -- shorter serial
//  trans chain on 4 waves before the barrier.
//  Per-pair math byte-identical to v5/v6 (scalar xyxy min/max, rcpf divide).
// ---------------------------------------------------------------------------
template<int NITER>   // >0: exact compile-time trip count; 0: generic runtime
__global__ __launch_bounds__(NT_THREADS, 4) void fused_cost_kernel(
    const float* __restrict__ pred_logits,  // [BS*QN, CN]
    const float* __restrict__ pred_boxes,   // [BS*QN, 4] cxcywh
    const int*   __restrict__ tgt_labels,   // [T]
    const float* __restrict__ tgt_boxes,    // [T, 4] cxcywh
    float*       __restrict__ out,          // [BS, QN/GS, T]
    int T)
{
    __shared__ __align__(16) float s_cc_t[CN * CC_STRIDE];  // [80][4] = 1280 B

    const int tid = threadIdx.x;
    const int qg0 = blockIdx.x;             // one query-group per block
    const int b   = blockIdx.y;
    const int n0  = b * QN + qg0 * GS;      // first of 3 pred rows

    // ---- focal class-cost rows, transposed into LDS (240 threads x 1) ----
    const float* lg0 = pred_logits + (size_t)n0 * CN;
    if (tid < ROWS * CN) {
        const float x = lg0[tid];
        const int r = tid / CN;
        const int c = tid - r * CN;
        float p = __fdividef(1.0f, 1.0f + __expf(-x));  // sigmoid
        float omp = 1.0f - p;
        float pos = ALPHA * omp * omp * (-__logf(p + EPS));
        float neg = (1.0f - ALPHA) * p * p * (-__logf(omp + EPS));
        s_cc_t[c * CC_STRIDE + r] = pos - neg;
    }

    // ---- pred rows -> wave-uniform registers (v6 exact) ----
    float Px0[ROWS], Py0[ROWS], Px1[ROWS], Py1[ROWS];
    float Pcx2[ROWS], Pcy2[ROWS], Pw[ROWS], Ph[ROWS], Pa[ROWS];
    #pragma unroll
    for (int r = 0; r < ROWS; ++r) {
        const float4 pb = ((const float4*)pred_boxes)[n0 + r];
        Pw[r]   = pb.z;               Ph[r]   = pb.w;
        Pa[r]   = pb.z * pb.w;
        Pcx2[r] = pb.x + pb.x;        Pcy2[r] = pb.y + pb.y;
        Px0[r]  = pb.x - 0.5f * pb.z; Py0[r]  = pb.y - 0.5f * pb.w;
        Px1[r]  = pb.x + 0.5f * pb.z; Py1[r]  = pb.y + 0.5f * pb.w;
    }
    __syncthreads();

    float* const o0 = out + (size_t)(b * (QN / GS) + qg0) * T;

    // body: per-t cost + group-max + store (byte-identical math to v5/v6)
    auto body = [&](int t, const float4 tr, int lab) {
        const float4 ccq = *((const float4*)&s_cc_t[lab * CC_STRIDE]);
        const float ccv[ROWS] = { ccq.x, ccq.y, ccq.z };

        const float tx0 = tr.x - 0.5f * tr.z, ty0 = tr.y - 0.5f * tr.w;
        const float tx1 = tr.x + 0.5f * tr.z, ty1 = tr.y + 0.5f * tr.w;
        const float ta  = tr.z * tr.w;
        const float tcx2 = tr.x + tr.x, tcy2 = tr.y + tr.y;

        float m = -3.402823466e+38f;
        #pragma unroll
        for (int i = 0; i < ROWS; ++i) {
            const float ix0 = fmaxf(Px0[i], tx0);
            const float iy0 = fmaxf(Py0[i], ty0);
            const float ix1 = fminf(Px1[i], tx1);
            const float iy1 = fminf(Py1[i], ty1);
            const float iw  = fmaxf(ix1 - ix0, 0.0f);
            const float ih  = fmaxf(iy1 - iy0, 0.0f);
            const float inter = iw * ih;

            const float ex0 = fminf(Px0[i], tx0);
            const float ey0 = fminf(Py0[i], ty0);
            const float ex1 = fmaxf(Px1[i], tx1);
            const float ey1 = fmaxf(Py1[i], ty1);
            const float earea = (ex1 - ex0) * (ey1 - ey0);

            const float uni = (Pa[i] + ta) - inter;

            const float h1 = fabsf(Pcx2[i] - tcx2) + fabsf(Pcy2[i] - tcy2);
            const float h2 = fabsf(Pw[i] - tr.z) + fabsf(Ph[i] - tr.w);
            const float l1 = fmaf(0.5f, h1, h2);

            const float num = fmaf(inter, earea, uni * uni);
            const float den = uni * earea;
            const float q   = num * __builtin_amdgcn_rcpf(den);

            const float cost = fmaf(5.0f, l1,
                                fmaf(2.0f, ccv[i], fmaf(-2.0f, q, 2.0f)));
            m = fmaxf(m, cost);
        }
        __builtin_nontemporal_store(m, o0 + t);
    };

    if constexpr (NITER > 0) {
        // depth-2 rolled pipeline: A = current, B = +1, prefetch C = +2
        int t = tid;
        float4 trA = ((const float4*)tgt_boxes)[t];
        int    laA = tgt_labels[t];
        float4 trB = ((const float4*)tgt_boxes)[t + NT_THREADS];   // <= 639: ok
        int    laB = tgt_labels[t + NT_THREADS];

        for (int it = 0; it < NITER; ++it) {
            const int tf = t + 2 * NT_THREADS;          // prefetch index
            const int tfc = (tf < T) ? tf : tid;        // clamped safe addr
            const float4 trC = ((const float4*)tgt_boxes)[tfc];
            const int    laC = tgt_labels[tfc];

            body(t, trA, laA);

            t += NT_THREADS;
            trA = trB; laA = laB;
            trB = trC; laB = laC;
        }
    } else {
        // generic rolled loop with depth-1 prefetch (v6-verified pattern)
        const int nIter = (T + NT_THREADS - 1) / NT_THREADS;
        int t = tid;
        int tl = (t < T) ? t : (T - 1);
        float4 tr  = ((const float4*)tgt_boxes)[tl];
        int    lab = tgt_labels[tl];
        for (int it = 0; it < nIter; ++it) {
            const int tn = t + NT_THREADS;
            const int tc = (tn < T) ? tn : tl;
            const float4 trn  = ((const float4*)tgt_boxes)[tc];
            const int    labn = tgt_labels[tc];
            if (t < T) body(t, tr, lab);
            t = tn; tl = tc; tr = trn; lab = labn;
        }
    }
}

extern "C" void kernel_launch(void* const* d_in, const int* in_sizes, int n_in,
                              void* d_out, int out_size, void* d_ws, size_t ws_size,
                              hipStream_t stream) {
    const float* pred_logits = (const float*)d_in[0];   // [16,900,80]
    const float* pred_boxes  = (const float*)d_in[1];   // [16,900,4]
    const int*   tgt_labels  = (const int*)d_in[2];     // [T]
    const float* tgt_boxes   = (const float*)d_in[3];   // [T,4]
    // d_in[4] = g_size (=3, hard-coded as GS)

    const int T = in_sizes[2];
    float* out = (float*)d_out;

    dim3 grid(QN / GS, BS);                              // 300 x 16 = 4800
    if (T == NT_THREADS * 5) {
        fused_cost_kernel<5><<<grid, NT_THREADS, 0, stream>>>(
            pred_logits, pred_boxes, tgt_labels, tgt_boxes, out, T);
    } else {
        fused_cost_kernel<0><<<grid, NT_THREADS, 0, stream>>>(
            pred_logits, pred_boxes, tgt_labels, tgt_boxes, out, T);
    }
}